// Round 6
// baseline (114.420 us; speedup 1.0000x reference)
//
#include <hip/hip_runtime.h>

// Lin2d: x_final = x @ (linMt)^N.  N-step linear recurrence == one matrix
// power + one streaming pass over x (64 MiB read + 64 MiB write).
//
// R2->R3: nt hints REGRESSED (+7 us — forfeit LLC hits from harness
//         restore/poison passes) -> plain cached access.
// R4->R5: 4xf4/thread vs 2xf4/thread NEUTRAL -> MLP not the limiter.
// R5->R6: hoist the binary-exponentiation matrix power out of the hot
//         kernel into a 1-thread prologue kernel writing M^N to d_ws.
//         Hot kernel becomes a pure branch-free stream: 1 uniform 16 B
//         matrix load + 2 f4 loads + 16 FMA + 2 f4 stores per thread.
//         Isolates "serial branchy prologue interferes with streaming".

typedef float f4 __attribute__((ext_vector_type(4)));

// --- prologue: M = linMt^N, one thread, result (row-major 2x2) -> ws ---
__global__ void lin2d_matpow(const float* __restrict__ linMt,
                             const int* __restrict__ Nptr,
                             float* __restrict__ m_out)
{
    if (threadIdx.x != 0 || blockIdx.x != 0) return;
    float b00 = linMt[0], b01 = linMt[1];
    float b10 = linMt[2], b11 = linMt[3];
    unsigned e = (unsigned)Nptr[0];
    float r00 = 1.f, r01 = 0.f, r10 = 0.f, r11 = 1.f;
    while (e) {
        if (e & 1u) {
            float t00 = r00*b00 + r01*b10;
            float t01 = r00*b01 + r01*b11;
            float t10 = r10*b00 + r11*b10;
            float t11 = r10*b01 + r11*b11;
            r00 = t00; r01 = t01; r10 = t10; r11 = t11;
        }
        e >>= 1;
        if (e) {
            float t00 = b00*b00 + b01*b10;
            float t01 = b00*b01 + b01*b11;
            float t10 = b10*b00 + b11*b10;
            float t11 = b10*b01 + b11*b11;
            b00 = t00; b01 = t01; b10 = t10; b11 = t11;
        }
    }
    f4 m = {r00, r01, r10, r11};
    *(f4*)m_out = m;
}

// --- hot kernel: pure stream, y = x @ M ---
__global__ __launch_bounds__(256)
void lin2d_apply(const float* __restrict__ x,
                 const float* __restrict__ m_in,
                 float* __restrict__ out,
                 long long n4, long long ntail_pairs)
{
    // Uniform 16 B matrix load (L2-hot after first wave).
    f4 m = *(const f4*)m_in;   // m.x=r00 m.y=r01 m.z=r10 m.w=r11

    const f4* __restrict__ xin = (const f4*)x;
    f4* __restrict__ o = (f4*)out;

    // 2 f4 per thread, block-strided: fully coalesced 16 B/lane bursts.
    long long i0 = (long long)blockIdx.x * 512 + threadIdx.x;
    long long i1 = i0 + 256;
    bool h0 = i0 < n4, h1 = i1 < n4;

    f4 v0 = {0,0,0,0}, v1 = {0,0,0,0};
    if (h0) v0 = xin[i0];
    if (h1) v1 = xin[i1];

    if (h0) {
        f4 w;
        w.x = v0.x * m.x + v0.y * m.z;
        w.y = v0.x * m.y + v0.y * m.w;
        w.z = v0.z * m.x + v0.w * m.z;
        w.w = v0.z * m.y + v0.w * m.w;
        o[i0] = w;
    }
    if (h1) {
        f4 w;
        w.x = v1.x * m.x + v1.y * m.z;
        w.y = v1.x * m.y + v1.y * m.w;
        w.z = v1.z * m.x + v1.w * m.z;
        w.w = v1.z * m.y + v1.w * m.w;
        o[i1] = w;
    }

    // Tail (total floats not divisible by 4) — scalar, one thread.
    if (blockIdx.x == 0 && threadIdx.x == 0) {
        for (long long p = 0; p < ntail_pairs; ++p) {
            long long b = n4 * 4 + p * 2;
            float x0 = x[b], x1 = x[b + 1];
            out[b]     = x0 * m.x + x1 * m.z;
            out[b + 1] = x0 * m.y + x1 * m.w;
        }
    }
}

extern "C" void kernel_launch(void* const* d_in, const int* in_sizes, int n_in,
                              void* d_out, int out_size, void* d_ws, size_t ws_size,
                              hipStream_t stream) {
    const float* x     = (const float*)d_in[0];   // (B, 2) fp32, flat
    const float* linMt = (const float*)d_in[1];   // 2x2 fp32
    const int*   N     = (const int*)d_in[2];     // scalar int as 1-elem array
    float* out = (float*)d_out;
    float* m_ws = (float*)d_ws;                   // 16 B scratch for M^N

    long long total = (long long)in_sizes[0];     // B*2 floats
    long long n4 = total / 4;                     // float4 chunks
    long long ntail_pairs = (total - n4 * 4) / 2;

    lin2d_matpow<<<1, 64, 0, stream>>>(linMt, N, m_ws);

    // Exact-size launch: 2 f4 per thread -> n4/512 blocks of 256.
    int blocks = (int)((n4 + 511) / 512);
    if (blocks < 1) blocks = 1;
    lin2d_apply<<<blocks, 256, 0, stream>>>(x, m_ws, out, n4, ntail_pairs);
}